// Round 5
// baseline (1456.499 us; speedup 1.0000x reference)
//
#include <hip/hip_runtime.h>
#include <stdint.h>

// ---------- sizes ----------
#define HID   4096
#define NB    32          // batch
#define PAST  2048
#define HQ    32
#define HKV   8
#define DH    128
#define SLOTS 65568
#define SCALE 0.088388347648318447f   // 1/sqrt(128)

// ws layout (float offsets)
#define OFF_QKV 0         // [6144][32] fp32 accumulators (q rows 0..4095, k 4096..5119, v 5120..6143)
#define OFF_QR  196608    // q_rope [32][4096]
#define OFF_KR  327680    // k_rope [32][1024]
#define OFF_VN  360448    // v_new  [32][1024]
#define OFF_PO  393216    // part_o [32][16][32][128]
#define OFF_PML 2490368   // part_ml[32][16][32][2]
#define OFF_OF  2523136   // o_final[32][4096]
#define OFF_OA  2654208   // out_acc[4096][32]

typedef unsigned int uint;

__device__ __forceinline__ unsigned short f2bf(float v) {  // RNE fp32->bf16
  uint u = __float_as_uint(v);
  u += 0x7fffu + ((u >> 16) & 1u);
  return (unsigned short)(u >> 16);
}
__device__ __forceinline__ float bflo(uint u) { return __uint_as_float(u << 16); }
__device__ __forceinline__ float bfhi(uint u) { return __uint_as_float(u & 0xffff0000u); }

__device__ __forceinline__ void fma8(float p, uint4 u, float* o) {
  o[0] += p * bflo(u.x); o[1] += p * bfhi(u.x);
  o[2] += p * bflo(u.y); o[3] += p * bfhi(u.y);
  o[4] += p * bflo(u.z); o[5] += p * bfhi(u.z);
  o[6] += p * bflo(u.w); o[7] += p * bfhi(u.w);
}

// ---------------- K1/K5: split-K fp32 GEMM  acc[o][b] += sum_h x[b][h]*W[o][h] -------------
__global__ __launch_bounds__(256) void gemm_split(
    const float* __restrict__ xin,                     // [32][4096]
    const float* __restrict__ wa, const float* __restrict__ wb, const float* __restrict__ wc,
    int bndA, int bndB, float* __restrict__ acc) {
  __shared__ __align__(16) float xs[32 * 256];
  const int h0 = blockIdx.y * 256;
  const int t = threadIdx.x;
  for (int i = t; i < 2048; i += 256) {                // 32 rows x 64 float4
    int bb = i >> 6, hh = (i & 63) << 2;
    *(float4*)&xs[bb * 256 + hh] = *(const float4*)&xin[bb * 4096 + h0 + hh];
  }
  __syncthreads();
  const int ocol = t & 63, bg = t >> 6;
  const int o0 = blockIdx.x * 256 + ocol * 4;
  const int b0 = bg * 8;
  const float* wrow[4];
#pragma unroll
  for (int i = 0; i < 4; ++i) {
    int o = o0 + i;
    const float* base = (o < bndA) ? (wa + (size_t)o * 4096)
                       : (o < bndB) ? (wb + (size_t)(o - bndA) * 4096)
                                    : (wc + (size_t)(o - bndB) * 4096);
    wrow[i] = base + h0;
  }
  float accr[4][8];
#pragma unroll
  for (int i = 0; i < 4; ++i)
#pragma unroll
    for (int j = 0; j < 8; ++j) accr[i][j] = 0.f;

  for (int h4 = 0; h4 < 256; h4 += 4) {
    float4 w[4];
#pragma unroll
    for (int i = 0; i < 4; ++i) w[i] = *(const float4*)(wrow[i] + h4);
    float4 xv[8];
#pragma unroll
    for (int j = 0; j < 8; ++j) xv[j] = *(const float4*)&xs[(b0 + j) * 256 + h4];
#pragma unroll
    for (int i = 0; i < 4; ++i)
#pragma unroll
      for (int j = 0; j < 8; ++j)
        accr[i][j] += w[i].x * xv[j].x + w[i].y * xv[j].y + w[i].z * xv[j].z + w[i].w * xv[j].w;
  }
#pragma unroll
  for (int i = 0; i < 4; ++i)
#pragma unroll
    for (int j = 0; j < 8; ++j)
      atomicAdd(&acc[(size_t)(o0 + i) * 32 + b0 + j], accr[i][j]);
}

// ---------------- K2: RoPE + stash q/k/v fp32 + write decode rows of kv_new (fp32) --------
__global__ __launch_bounds__(256) void rope_prep(
    const float* __restrict__ acc, const float* __restrict__ cosp, const float* __restrict__ sinp,
    const int* __restrict__ decode_index,
    float* __restrict__ q_rope, float* __restrict__ k_rope, float* __restrict__ v_new,
    float* __restrict__ out_kv) {
  const int b = blockIdx.x, t = threadIdx.x;
  const size_t slot = (size_t)decode_index[b];
  for (int i = t; i < 4096; i += 256) {                       // q: 32 heads x 128
    int d = i & 127;
    float c = cosp[b * 128 + d], s = sinp[b * 128 + d];
    float v = acc[(size_t)i * 32 + b];
    float vo = acc[(size_t)((d < 64) ? i + 64 : i - 64) * 32 + b];
    float rot = (d < 64) ? -vo : vo;
    q_rope[b * 4096 + i] = v * c + rot * s;
  }
  for (int i = t; i < 1024; i += 256) {                       // k: 8 heads x 128
    int d = i & 127, o = 4096 + i;
    float c = cosp[b * 128 + d], s = sinp[b * 128 + d];
    float v = acc[(size_t)o * 32 + b];
    float vo = acc[(size_t)((d < 64) ? o + 64 : o - 64) * 32 + b];
    float rot = (d < 64) ? -vo : vo;
    float kr = v * c + rot * s;
    k_rope[b * 1024 + i] = kr;
    out_kv[slot * 2048 + i] = kr;                             // K half
  }
  for (int i = t; i < 1024; i += 256) {                       // v (no rope)
    float v = acc[(size_t)(5120 + i) * 32 + b];
    v_new[b * 1024 + i] = v;
    out_kv[slot * 2048 + 1024 + i] = v;
  }
}

// ---------------- K3: fused kv copy (fp32) + flash-decode partials ------------------------
// grid (16 s-tiles, 32 b), block 256 = 32 qh x 8 s-lanes. Tile = 128 s, chunks of 8 slots.
#define KSTR 1032  // bf16 elems per staged slot row half (1024 + 8 pad)
__global__ __launch_bounds__(256) void attn_partial(
    const float* __restrict__ kv_buffer, const int* __restrict__ select_index,
    const float* __restrict__ q_rope, float* __restrict__ out_kv,
    float* __restrict__ part_o, float* __restrict__ part_ml) {
  __shared__ __align__(16) unsigned short qs[32 * 136];   // q bf16, padded rows
  __shared__ __align__(16) unsigned short ks[8 * KSTR];
  __shared__ __align__(16) unsigned short vs[8 * KSTR];
  const int tile = blockIdx.x, b = blockIdx.y, t = threadIdx.x;
  for (int i = t; i < 4096; i += 256) {
    int qh = i >> 7, d = i & 127;
    qs[qh * 136 + d] = f2bf(q_rope[b * 4096 + i]);
  }
  const int qh = t >> 3, j = t & 7, g = qh >> 2;
  const int lane = t & 63, lbase = lane & ~7;
  float m_run = -1e30f, l_run = 0.f;
  float oacc[16];
#pragma unroll
  for (int k = 0; k < 16; ++k) oacc[k] = 0.f;
  const int* sel = select_index + b * 2048 + tile * 128;

  for (int ch = 0; ch < 16; ++ch) {
    __syncthreads();                                      // LDS reuse guard (also covers qs once)
    // stage 8 gathered slots: HBM fp32 -> (fp32 kv_new writeback) + (bf16 LDS)
    for (int i = t; i < 4096; i += 256) {                 // 4096 float4 total
      int sl = i >> 9;
      int pos = (i & 511) << 2;
      size_t gbase = (size_t)sel[ch * 8 + sl] * 2048 + pos;
      float4 f = *(const float4*)&kv_buffer[gbase];
      *(float4*)&out_kv[gbase] = f;                       // exact fp32 copy
      uint2 pk;
      pk.x = (uint)f2bf(f.x) | ((uint)f2bf(f.y) << 16);
      pk.y = (uint)f2bf(f.z) | ((uint)f2bf(f.w) << 16);
      unsigned short* dst = (pos < 1024) ? &ks[sl * KSTR + pos] : &vs[sl * KSTR + pos - 1024];
      *(uint2*)dst = pk;
    }
    __syncthreads();
    // scores: thread (qh, j) computes q[qh] . K[s=ch*8+j][g]
    const unsigned short* qp = qs + qh * 136;
    const unsigned short* kp = ks + j * KSTR + g * 128;
    float dot = 0.f;
#pragma unroll
    for (int d0 = 0; d0 < 128; d0 += 8) {
      uint4 qu = *(const uint4*)(qp + d0);
      uint4 ku = *(const uint4*)(kp + d0);
      dot += bflo(qu.x) * bflo(ku.x) + bfhi(qu.x) * bfhi(ku.x);
      dot += bflo(qu.y) * bflo(ku.y) + bfhi(qu.y) * bfhi(ku.y);
      dot += bflo(qu.z) * bflo(ku.z) + bfhi(qu.z) * bfhi(ku.z);
      dot += bflo(qu.w) * bflo(ku.w) + bfhi(qu.w) * bfhi(ku.w);
    }
    float sc = dot * SCALE;
    // online softmax across the 8-lane group (same qh)
    float cmax = sc;
#pragma unroll
    for (int off = 1; off < 8; off <<= 1) cmax = fmaxf(cmax, __shfl_xor(cmax, off, 64));
    float mnew = fmaxf(m_run, cmax);
    float p = __expf(sc - mnew);
    float psum = p;
#pragma unroll
    for (int off = 1; off < 8; off <<= 1) psum += __shfl_xor(psum, off, 64);
    float corr = __expf(m_run - mnew);
    m_run = mnew;
    l_run = l_run * corr + psum;
#pragma unroll
    for (int k = 0; k < 16; ++k) oacc[k] *= corr;
    // PV: thread owns d-slice [j*16, j*16+16)
#pragma unroll
    for (int jj = 0; jj < 8; ++jj) {
      float pj = __shfl(p, lbase | jj, 64);
      const unsigned short* vp = vs + jj * KSTR + g * 128 + j * 16;
      uint4 v0 = *(const uint4*)(vp);
      uint4 v1 = *(const uint4*)(vp + 8);
      fma8(pj, v0, oacc);
      fma8(pj, v1, oacc + 8);
    }
  }
  float* po = part_o + (((size_t)b * 16 + tile) * 32 + qh) * 128 + j * 16;
#pragma unroll
  for (int k = 0; k < 16; ++k) po[k] = oacc[k];
  if (j == 0) {
    size_t mi = (((size_t)b * 16 + tile) * 32 + qh) * 2;
    part_ml[mi] = m_run;
    part_ml[mi + 1] = l_run;
  }
}

// ---------------- K4: combine 16 tile-partials + new-token term --------------------------
__global__ __launch_bounds__(64) void combine(
    const float* __restrict__ part_o, const float* __restrict__ part_ml,
    const float* __restrict__ q_rope, const float* __restrict__ k_rope,
    const float* __restrict__ v_new, float* __restrict__ o_final) {
  const int bq = blockIdx.x, b = bq >> 5, qh = bq & 31, g = qh >> 2;
  const int lane = threadIdx.x;
  float part = 0.f;
#pragma unroll
  for (int k = 0; k < 2; ++k) {
    int d = lane + k * 64;
    part += q_rope[b * 4096 + qh * 128 + d] * k_rope[b * 1024 + g * 128 + d];
  }
#pragma unroll
  for (int off = 1; off < 64; off <<= 1) part += __shfl_xor(part, off, 64);
  float s_new = part * SCALE;
  float M = s_new;
  float mt[16], lt[16];
#pragma unroll
  for (int tt = 0; tt < 16; ++tt) {
    size_t mi = (((size_t)b * 16 + tt) * 32 + qh) * 2;
    mt[tt] = part_ml[mi]; lt[tt] = part_ml[mi + 1];
    M = fmaxf(M, mt[tt]);
  }
  float pnew = __expf(s_new - M);
  float L = pnew;
  float wt[16];
#pragma unroll
  for (int tt = 0; tt < 16; ++tt) { wt[tt] = __expf(mt[tt] - M); L += lt[tt] * wt[tt]; }
  float invL = 1.f / L;
#pragma unroll
  for (int k = 0; k < 2; ++k) {
    int d = lane + k * 64;
    float a = pnew * v_new[b * 1024 + g * 128 + d];
#pragma unroll
    for (int tt = 0; tt < 16; ++tt)
      a += part_o[(((size_t)b * 16 + tt) * 32 + qh) * 128 + d] * wt[tt];
    o_final[b * 4096 + qh * 128 + d] = a * invL;
  }
}

// ---------------- K6: out_acc[h][b] -> fp32 out[b][h] ------------------------------------
__global__ __launch_bounds__(256) void finalize_out(const float* __restrict__ out_acc,
                                                    float* __restrict__ dout) {
  int i = blockIdx.x * 256 + threadIdx.x;
  if (i < NB * HID) {
    int b = i >> 12, h = i & 4095;
    dout[i] = out_acc[(size_t)h * 32 + b];
  }
}

extern "C" void kernel_launch(void* const* d_in, const int* in_sizes, int n_in,
                              void* d_out, int out_size, void* d_ws, size_t ws_size,
                              hipStream_t stream) {
  const float* x    = (const float*)d_in[0];
  const float* wq   = (const float*)d_in[1];
  const float* wk   = (const float*)d_in[2];
  const float* wv   = (const float*)d_in[3];
  const float* wo   = (const float*)d_in[4];
  const float* cosp = (const float*)d_in[5];
  const float* sinp = (const float*)d_in[6];
  const float* kvb  = (const float*)d_in[7];
  const int*   sel  = (const int*)d_in[8];
  const int*   dec  = (const int*)d_in[9];

  float* dout   = (float*)d_out;
  float* out_kv = dout + (size_t)NB * HID;              // kv_new region (fp32)

  float* ws      = (float*)d_ws;
  float* qkv_acc = ws + OFF_QKV;
  float* q_rope  = ws + OFF_QR;
  float* k_rope  = ws + OFF_KR;
  float* v_new   = ws + OFF_VN;
  float* part_o  = ws + OFF_PO;
  float* part_ml = ws + OFF_PML;
  float* o_final = ws + OFF_OF;
  float* out_acc = ws + OFF_OA;

  hipMemsetAsync(qkv_acc, 0, 196608 * sizeof(float), stream);
  hipMemsetAsync(out_acc, 0, 131072 * sizeof(float), stream);

  gemm_split<<<dim3(24, 16), 256, 0, stream>>>(x, wq, wk, wv, 4096, 5120, qkv_acc);
  rope_prep<<<32, 256, 0, stream>>>(qkv_acc, cosp, sinp, dec, q_rope, k_rope, v_new, out_kv);
  attn_partial<<<dim3(16, 32), 256, 0, stream>>>(kvb, sel, q_rope, out_kv, part_o, part_ml);
  combine<<<1024, 64, 0, stream>>>(part_o, part_ml, q_rope, k_rope, v_new, o_final);
  gemm_split<<<dim3(16, 16), 256, 0, stream>>>(o_final, wo, wo, wo, 4096, 4096, out_acc);
  finalize_out<<<512, 256, 0, stream>>>(out_acc, dout);
}